// Round 1
// baseline (785.368 us; speedup 1.0000x reference)
//
#include <hip/hip_runtime.h>

// SVF scaling-and-squaring: 16 steps of warp <- warp + sample(warp, id + warp)
// Shapes: v [1,3,160,160,160] f32, identity_grid [1,160,160,160,3] f32 (recomputed
// analytically on device -- bitwise identical to (2*i+1)/160 - 1 in fp32).
// Intermediate warp buffers are channel-interleaved [D][H][W][3] for gather locality.

constexpr int S   = 160;
constexpr int SS  = S * S;          // 25600
constexpr long long VOXLL = (long long)S * S * S;  // 4,096,000
constexpr int VOX = (int)VOXLL;
constexpr int THREADS = 256;
constexpr int BLOCKS  = VOX / THREADS;  // 16000 exactly

__device__ __forceinline__ float idcoord(int u) {
    // matches jnp: (2.0*arange + 1.0)/160.0 - 1.0 in fp32 (IEEE divide)
    return (2.0f * (float)u + 1.0f) / 160.0f - 1.0f;
}

// SRC_PLANAR: source is v in [C][D][H][W] layout (step 1), scaled by `scale`.
// FINAL: write planar d_out with identity added (step 16).
template <bool SRC_PLANAR, bool FINAL>
__global__ __launch_bounds__(THREADS) void svf_step(const float* __restrict__ src,
                                                    float* __restrict__ dst,
                                                    float scale) {
    const int idx = blockIdx.x * THREADS + threadIdx.x;
    const int x = idx % S;
    const int t = idx / S;
    const int y = t % S;
    const int z = t / S;

    // own warp value (= sample of warp at this voxel, pre-scaled)
    float w0, w1, w2;
    if (SRC_PLANAR) {
        w0 = src[idx] * scale;
        w1 = src[idx + VOX] * scale;
        w2 = src[idx + 2 * VOX] * scale;
    } else {
        const float* p = src + (size_t)idx * 3;
        w0 = p[0]; w1 = p[1]; w2 = p[2];
    }

    const float ix = idcoord(x);
    const float iy = idcoord(y);
    const float iz = idcoord(z);

    // unnormalize exactly like the reference: ((g + 1)*S - 1)*0.5, clip to border
    float gx = ((ix + w0 + 1.0f) * 160.0f - 1.0f) * 0.5f;
    float gy = ((iy + w1 + 1.0f) * 160.0f - 1.0f) * 0.5f;
    float gz = ((iz + w2 + 1.0f) * 160.0f - 1.0f) * 0.5f;
    gx = fminf(fmaxf(gx, 0.0f), 159.0f);
    gy = fminf(fmaxf(gy, 0.0f), 159.0f);
    gz = fminf(fmaxf(gz, 0.0f), 159.0f);

    const float x0f = floorf(gx), y0f = floorf(gy), z0f = floorf(gz);
    const float fx = gx - x0f, fy = gy - y0f, fz = gz - z0f;
    const int x0 = (int)x0f, y0 = (int)y0f, z0 = (int)z0f;
    const int x1 = min(x0 + 1, S - 1);
    const int y1 = min(y0 + 1, S - 1);
    const int z1 = min(z0 + 1, S - 1);

    const float ofx = 1.0f - fx, ofy = 1.0f - fy, ofz = 1.0f - fz;

    float r0, r1, r2;
    if (SRC_PLANAR) {
        // planar gather (step 1: displacements are ~2^-16 voxels, perfect locality)
        #pragma unroll
        for (int c = 0; c < 3; ++c) {
            const float* pc = src + (size_t)c * VOX;
            const int b00 = z0 * SS + y0 * S;
            const int b01 = z0 * SS + y1 * S;
            const int b10 = z1 * SS + y0 * S;
            const int b11 = z1 * SS + y1 * S;
            float v000 = pc[b00 + x0] * scale, v001 = pc[b00 + x1] * scale;
            float v010 = pc[b01 + x0] * scale, v011 = pc[b01 + x1] * scale;
            float v100 = pc[b10 + x0] * scale, v101 = pc[b10 + x1] * scale;
            float v110 = pc[b11 + x0] * scale, v111 = pc[b11 + x1] * scale;
            float c00 = v000 * ofx + v001 * fx;
            float c01 = v010 * ofx + v011 * fx;
            float c10 = v100 * ofx + v101 * fx;
            float c11 = v110 * ofx + v111 * fx;
            float r = (c00 * ofy + c01 * fy) * ofz + (c10 * ofy + c11 * fy) * fz;
            if (c == 0) r0 = r; else if (c == 1) r1 = r; else r2 = r;
        }
    } else {
        // interleaved gather: 3 channels x (x0,x1) of a (z,y) corner = 24 contiguous B
        const size_t b00 = ((size_t)(z0 * SS + y0 * S)) * 3;
        const size_t b01 = ((size_t)(z0 * SS + y1 * S)) * 3;
        const size_t b10 = ((size_t)(z1 * SS + y0 * S)) * 3;
        const size_t b11 = ((size_t)(z1 * SS + y1 * S)) * 3;
        const size_t ox0 = (size_t)x0 * 3, ox1 = (size_t)x1 * 3;
        float r[3];
        #pragma unroll
        for (int c = 0; c < 3; ++c) {
            float v000 = src[b00 + ox0 + c], v001 = src[b00 + ox1 + c];
            float v010 = src[b01 + ox0 + c], v011 = src[b01 + ox1 + c];
            float v100 = src[b10 + ox0 + c], v101 = src[b10 + ox1 + c];
            float v110 = src[b11 + ox0 + c], v111 = src[b11 + ox1 + c];
            float c00 = v000 * ofx + v001 * fx;
            float c01 = v010 * ofx + v011 * fx;
            float c10 = v100 * ofx + v101 * fx;
            float c11 = v110 * ofx + v111 * fx;
            r[c] = (c00 * ofy + c01 * fy) * ofz + (c10 * ofy + c11 * fy) * fz;
        }
        r0 = r[0]; r1 = r[1]; r2 = r[2];
    }

    const float n0 = w0 + r0;
    const float n1 = w1 + r1;
    const float n2 = w2 + r2;

    if (FINAL) {
        // out = transpose(identity) + warp, planar [C][D][H][W]
        dst[idx]           = ix + n0;
        dst[idx + VOX]     = iy + n1;
        dst[idx + 2 * VOX] = iz + n2;
    } else {
        float* q = dst + (size_t)idx * 3;
        q[0] = n0; q[1] = n1; q[2] = n2;
    }
}

extern "C" void kernel_launch(void* const* d_in, const int* in_sizes, int n_in,
                              void* d_out, int out_size, void* d_ws, size_t ws_size,
                              hipStream_t stream) {
    // in[0] = identity_grid (unused: recomputed analytically), in[1] = v
    const float* v = (const float*)d_in[1];
    float* out = (float*)d_out;
    float* ws  = (float*)d_ws;   // needs 3*160^3*4 = 49.15 MB

    const float s = 1.0f / 65536.0f;  // 2^-16, exact

    // step 1: v (planar, scaled) -> ws (interleaved)
    svf_step<true, false><<<BLOCKS, THREADS, 0, stream>>>(v, ws, s);
    // steps 2..15: ping-pong ws <-> d_out (both used as interleaved scratch)
    for (int k = 2; k <= 15; ++k) {
        if ((k & 1) == 0)
            svf_step<false, false><<<BLOCKS, THREADS, 0, stream>>>(ws, out, 1.0f);
        else
            svf_step<false, false><<<BLOCKS, THREADS, 0, stream>>>(out, ws, 1.0f);
    }
    // step 16: ws -> d_out, planar, + identity
    svf_step<false, true><<<BLOCKS, THREADS, 0, stream>>>(ws, out, 1.0f);
}

// Round 2
// 706.580 us; speedup vs baseline: 1.1115x; 1.1115x over previous
//
#include <hip/hip_runtime.h>

// SVF scaling-and-squaring: 16 steps of warp <- warp + sample(warp, id + warp)
// Intermediates channel-interleaved [D][H][W][3]; gathers vectorized as
// dwordx4+dwordx2 per trilinear corner; XCD-chunked block swizzle for L2 locality.

constexpr int S   = 160;
constexpr int SS  = S * S;            // 25600
constexpr int VOX = S * S * S;        // 4,096,000
constexpr int THREADS = 256;
constexpr int BLOCKS  = VOX / THREADS;   // 16000
constexpr int NXCD  = 8;
constexpr int CHUNK = BLOCKS / NXCD;     // 2000 (exact)

__device__ __forceinline__ float idcoord(int u) {
    // matches jnp: (2.0*arange + 1.0)/160.0 - 1.0 in fp32
    return (2.0f * (float)u + 1.0f) / 160.0f - 1.0f;
}

// unaligned-safe vector loads (dword alignment suffices on gfx9+)
__device__ __forceinline__ float4 ld4u(const float* p) { float4 r; __builtin_memcpy(&r, p, 16); return r; }
__device__ __forceinline__ float2 ld2u(const float* p) { float2 r; __builtin_memcpy(&r, p, 8);  return r; }

template <bool SRC_PLANAR, bool FINAL>
__global__ __launch_bounds__(THREADS) void svf_step(const float* __restrict__ src,
                                                    float* __restrict__ dst,
                                                    float scale) {
    // XCD-chunked swizzle: hw block b (XCD = b&7) -> contiguous work chunk per XCD
    const int b   = blockIdx.x;
    const int blk = (b & (NXCD - 1)) * CHUNK + (b >> 3);
    const int idx = blk * THREADS + threadIdx.x;

    const int x = idx % S;
    const int t = idx / S;
    const int y = t % S;
    const int z = t / S;

    // own warp value (pre-scaled)
    float w0, w1, w2;
    if (SRC_PLANAR) {
        w0 = src[idx] * scale;
        w1 = src[idx + VOX] * scale;
        w2 = src[idx + 2 * VOX] * scale;
    } else {
        const float* p = src + (size_t)idx * 3;
        float2 w01 = ld2u(p);
        w0 = w01.x; w1 = w01.y; w2 = p[2];
    }

    const float ix = idcoord(x);
    const float iy = idcoord(y);
    const float iz = idcoord(z);

    float gx = ((ix + w0 + 1.0f) * 160.0f - 1.0f) * 0.5f;
    float gy = ((iy + w1 + 1.0f) * 160.0f - 1.0f) * 0.5f;
    float gz = ((iz + w2 + 1.0f) * 160.0f - 1.0f) * 0.5f;
    gx = fminf(fmaxf(gx, 0.0f), 159.0f);
    gy = fminf(fmaxf(gy, 0.0f), 159.0f);
    gz = fminf(fmaxf(gz, 0.0f), 159.0f);

    const float x0f = floorf(gx), y0f = floorf(gy), z0f = floorf(gz);
    const float fx = gx - x0f, fy = gy - y0f, fz = gz - z0f;
    const int x0 = (int)x0f, y0 = (int)y0f, z0 = (int)z0f;
    const int x1 = min(x0 + 1, S - 1);
    const int y1 = min(y0 + 1, S - 1);
    const int z1 = min(z0 + 1, S - 1);
    const float ofx = 1.0f - fx, ofy = 1.0f - fy, ofz = 1.0f - fz;
    const bool xn = (x1 != x0);   // false only when x0==159 (then fx==0)

    float r0, r1, r2;
    if (SRC_PLANAR) {
        // planar gather, vectorized: per channel per corner one ld2 covers x0,x1
        #pragma unroll
        for (int c = 0; c < 3; ++c) {
            const float* pc = src + (size_t)c * VOX;
            const int b00 = z0 * SS + y0 * S;
            const int b01 = z0 * SS + y1 * S;
            const int b10 = z1 * SS + y0 * S;
            const int b11 = z1 * SS + y1 * S;
            float2 A00 = ld2u(pc + b00 + x0);
            float2 A01 = ld2u(pc + b01 + x0);
            float2 A10 = ld2u(pc + b10 + x0);
            float2 A11 = ld2u(pc + b11 + x0);
            float v001 = (xn ? A00.y : A00.x) * scale;
            float v011 = (xn ? A01.y : A01.x) * scale;
            float v101 = (xn ? A10.y : A10.x) * scale;
            float v111 = (xn ? A11.y : A11.x) * scale;
            float c00 = (A00.x * scale) * ofx + v001 * fx;
            float c01 = (A01.x * scale) * ofx + v011 * fx;
            float c10 = (A10.x * scale) * ofx + v101 * fx;
            float c11 = (A11.x * scale) * ofx + v111 * fx;
            float r = (c00 * ofy + c01 * fy) * ofz + (c10 * ofy + c11 * fy) * fz;
            if (c == 0) r0 = r; else if (c == 1) r1 = r; else r2 = r;
        }
    } else {
        // interleaved gather: per corner dwordx4 (c0..c2 of x0, c0 of x0+1)
        // + dwordx2 (c1,c2 of x1) = exactly the 6 dwords needed
        const int ox0 = x0 * 3, ox1 = x1 * 3;
        float g[3][4];  // [channel][corner]
        const int rb[4] = { (z0 * SS + y0 * S) * 3, (z0 * SS + y1 * S) * 3,
                            (z1 * SS + y0 * S) * 3, (z1 * SS + y1 * S) * 3 };
        #pragma unroll
        for (int q = 0; q < 4; ++q) {
            const float* rp = src + rb[q];
            float4 A = ld4u(rp + ox0);
            float2 B = ld2u(rp + ox1 + 1);
            float v1c0 = xn ? A.w : A.x;
            g[0][q] = A.x * ofx + v1c0 * fx;
            g[1][q] = A.y * ofx + B.x  * fx;
            g[2][q] = A.z * ofx + B.y  * fx;
        }
        r0 = (g[0][0] * ofy + g[0][1] * fy) * ofz + (g[0][2] * ofy + g[0][3] * fy) * fz;
        r1 = (g[1][0] * ofy + g[1][1] * fy) * ofz + (g[1][2] * ofy + g[1][3] * fy) * fz;
        r2 = (g[2][0] * ofy + g[2][1] * fy) * ofz + (g[2][2] * ofy + g[2][3] * fy) * fz;
    }

    const float n0 = w0 + r0;
    const float n1 = w1 + r1;
    const float n2 = w2 + r2;

    if (FINAL) {
        dst[idx]           = ix + n0;
        dst[idx + VOX]     = iy + n1;
        dst[idx + 2 * VOX] = iz + n2;
    } else {
        float* q = dst + (size_t)idx * 3;
        float2 st = make_float2(n0, n1);
        __builtin_memcpy(q, &st, 8);
        q[2] = n2;
    }
}

extern "C" void kernel_launch(void* const* d_in, const int* in_sizes, int n_in,
                              void* d_out, int out_size, void* d_ws, size_t ws_size,
                              hipStream_t stream) {
    // in[0] = identity_grid (recomputed analytically), in[1] = v
    const float* v = (const float*)d_in[1];
    float* out = (float*)d_out;
    float* ws  = (float*)d_ws;   // 3*160^3*4 = 49.15 MB used

    const float s = 1.0f / 65536.0f;  // 2^-16, exact

    svf_step<true, false><<<BLOCKS, THREADS, 0, stream>>>(v, ws, s);
    for (int k = 2; k <= 15; ++k) {
        if ((k & 1) == 0)
            svf_step<false, false><<<BLOCKS, THREADS, 0, stream>>>(ws, out, 1.0f);
        else
            svf_step<false, false><<<BLOCKS, THREADS, 0, stream>>>(out, ws, 1.0f);
    }
    svf_step<false, true><<<BLOCKS, THREADS, 0, stream>>>(ws, out, 1.0f);
}

// Round 3
// 589.196 us; speedup vs baseline: 1.3329x; 1.1992x over previous
//
#include <hip/hip_runtime.h>

// SVF scaling-and-squaring: 16 steps of warp <- warp + sample(warp, id + warp)
// Intermediate warp buffers use a y/z-paired brick layout so a trilinear
// stencil touches ~3.6 cache lines instead of ~4.7:
//   float index of voxel (x,y,z) =
//     (((z>>1)*80 + (y>>1))*160 + x)*12 + ((z&1)*2 + (y&1))*3
// i.e. [zb][yb][x][lz][ly][c], 48 B per (x, y-pair, z-pair) unit.
// Each stencil voxel is one dwordx4 (12 B used + 4 B slop).

constexpr int S   = 160;
constexpr int SS  = S * S;
constexpr int VOX = S * S * S;        // 4,096,000
constexpr int THREADS = 256;
constexpr int BLOCKS  = VOX / THREADS;   // 16000
constexpr int NXCD  = 8;
constexpr int CHUNK = BLOCKS / NXCD;     // 2000

__device__ __forceinline__ float idcoord(int u) {
    // matches jnp: (2.0*arange + 1.0)/160.0 - 1.0 in fp32
    return (2.0f * (float)u + 1.0f) / 160.0f - 1.0f;
}

__device__ __forceinline__ float4 ld4u(const float* p) { float4 r; __builtin_memcpy(&r, p, 16); return r; }
__device__ __forceinline__ float2 ld2u(const float* p) { float2 r; __builtin_memcpy(&r, p, 8);  return r; }

// row base (float index, without the x term) for gather row (yj, zk)
__device__ __forceinline__ int rowb(int yj, int zk) {
    return (((zk >> 1) * 80 + (yj >> 1)) * S) * 12 + ((zk & 1) * 2 + (yj & 1)) * 3;
}

// MODE 0: planar v source (scaled) -> brick dst      (step 1)
// MODE 1: brick source -> brick dst                  (steps 2..15)
// MODE 2: brick source -> planar dst + identity      (step 16)
template <int MODE>
__global__ __launch_bounds__(THREADS) void svf_step(const float* __restrict__ src,
                                                    float* __restrict__ dst,
                                                    float scale) {
    const int b   = blockIdx.x;
    const int blk = (b & (NXCD - 1)) * CHUNK + (b >> 3);
    const int m   = blk * THREADS + threadIdx.x;

    // decode voxel from memory-linear id (brick order):
    // m = ((unit*160 + x)*4 + lr), unit = zb*80 + yb, lr = lz*2 + ly
    const int lr = m & 3;
    const int t  = m >> 2;
    const int x  = t % S;
    const int u  = t / S;
    const int y  = (u % 80) * 2 + (lr & 1);
    const int z  = (u / 80) * 2 + (lr >> 1);

    const int f = m * 3;  // own float index in brick layout

    float w0, w1, w2;
    if (MODE == 0) {
        const int pidx = (z * S + y) * S + x;  // planar index
        w0 = src[pidx] * scale;
        w1 = src[pidx + VOX] * scale;
        w2 = src[pidx + 2 * VOX] * scale;
    } else {
        float4 own = ld4u(src + f);
        w0 = own.x; w1 = own.y; w2 = own.z;
    }

    const float ix = idcoord(x);
    const float iy = idcoord(y);
    const float iz = idcoord(z);

    float gx = ((ix + w0 + 1.0f) * 160.0f - 1.0f) * 0.5f;
    float gy = ((iy + w1 + 1.0f) * 160.0f - 1.0f) * 0.5f;
    float gz = ((iz + w2 + 1.0f) * 160.0f - 1.0f) * 0.5f;
    gx = fminf(fmaxf(gx, 0.0f), 159.0f);
    gy = fminf(fmaxf(gy, 0.0f), 159.0f);
    gz = fminf(fmaxf(gz, 0.0f), 159.0f);

    const float x0f = floorf(gx), y0f = floorf(gy), z0f = floorf(gz);
    const float fx = gx - x0f, fy = gy - y0f, fz = gz - z0f;
    const int x0 = (int)x0f, y0 = (int)y0f, z0 = (int)z0f;
    const int x1 = min(x0 + 1, S - 1);
    const int y1 = min(y0 + 1, S - 1);
    const int z1 = min(z0 + 1, S - 1);
    const float ofx = 1.0f - fx, ofy = 1.0f - fy, ofz = 1.0f - fz;

    float r0, r1, r2;
    if (MODE == 0) {
        // planar gather from v (step 1: displacements ~2^-16 voxels, local)
        const bool xn = (x1 != x0);
        #pragma unroll
        for (int c = 0; c < 3; ++c) {
            const float* pc = src + (size_t)c * VOX;
            const int b00 = z0 * SS + y0 * S;
            const int b01 = z0 * SS + y1 * S;
            const int b10 = z1 * SS + y0 * S;
            const int b11 = z1 * SS + y1 * S;
            float2 A00 = ld2u(pc + b00 + x0);
            float2 A01 = ld2u(pc + b01 + x0);
            float2 A10 = ld2u(pc + b10 + x0);
            float2 A11 = ld2u(pc + b11 + x0);
            float v001 = (xn ? A00.y : A00.x) * scale;
            float v011 = (xn ? A01.y : A01.x) * scale;
            float v101 = (xn ? A10.y : A10.x) * scale;
            float v111 = (xn ? A11.y : A11.x) * scale;
            float c00 = (A00.x * scale) * ofx + v001 * fx;
            float c01 = (A01.x * scale) * ofx + v011 * fx;
            float c10 = (A10.x * scale) * ofx + v101 * fx;
            float c11 = (A11.x * scale) * ofx + v111 * fx;
            float r = (c00 * ofy + c01 * fy) * ofz + (c10 * ofy + c11 * fy) * fz;
            if (c == 0) r0 = r; else if (c == 1) r1 = r; else r2 = r;
        }
    } else {
        // brick gather: 8 stencil voxels, one dwordx4 each (12 B used)
        const int rb4[4] = { rowb(y0, z0), rowb(y1, z0), rowb(y0, z1), rowb(y1, z1) };
        const int xo0 = x0 * 12, xo1 = x1 * 12;
        float g0[4], g1[4], g2[4];
        #pragma unroll
        for (int q = 0; q < 4; ++q) {
            float4 A = ld4u(src + rb4[q] + xo0);
            float4 B = ld4u(src + rb4[q] + xo1);
            g0[q] = A.x * ofx + B.x * fx;
            g1[q] = A.y * ofx + B.y * fx;
            g2[q] = A.z * ofx + B.z * fx;
        }
        r0 = (g0[0] * ofy + g0[1] * fy) * ofz + (g0[2] * ofy + g0[3] * fy) * fz;
        r1 = (g1[0] * ofy + g1[1] * fy) * ofz + (g1[2] * ofy + g1[3] * fy) * fz;
        r2 = (g2[0] * ofy + g2[1] * fy) * ofz + (g2[2] * ofy + g2[3] * fy) * fz;
    }

    const float n0 = w0 + r0;
    const float n1 = w1 + r1;
    const float n2 = w2 + r2;

    if (MODE == 2) {
        const int pidx = (z * S + y) * S + x;
        dst[pidx]           = ix + n0;
        dst[pidx + VOX]     = iy + n1;
        dst[pidx + 2 * VOX] = iz + n2;
    } else {
        float2 st = make_float2(n0, n1);
        __builtin_memcpy(dst + f, &st, 8);
        dst[f + 2] = n2;
    }
}

extern "C" void kernel_launch(void* const* d_in, const int* in_sizes, int n_in,
                              void* d_out, int out_size, void* d_ws, size_t ws_size,
                              hipStream_t stream) {
    // in[0] = identity_grid (recomputed analytically), in[1] = v
    const float* v = (const float*)d_in[1];
    float* out = (float*)d_out;
    float* ws  = (float*)d_ws;   // 3*160^3*4 = 49.15 MB used

    const float s = 1.0f / 65536.0f;  // 2^-16, exact

    // step 1: v (planar, scaled) -> ws (brick)
    svf_step<0><<<BLOCKS, THREADS, 0, stream>>>(v, ws, s);
    // steps 2..15: ping-pong ws <-> d_out (both brick scratch)
    for (int k = 2; k <= 15; ++k) {
        if ((k & 1) == 0)
            svf_step<1><<<BLOCKS, THREADS, 0, stream>>>(ws, out, 1.0f);
        else
            svf_step<1><<<BLOCKS, THREADS, 0, stream>>>(out, ws, 1.0f);
    }
    // step 16: ws (brick) -> d_out planar + identity
    svf_step<2><<<BLOCKS, THREADS, 0, stream>>>(ws, out, 1.0f);
}